// Round 2
// baseline (2522.880 us; speedup 1.0000x reference)
//
#include <hip/hip_runtime.h>

#define B_    32
#define T_    512
#define I_    256
#define H_    512
#define PB    16          // blocks per direction
#define NB_LAUNCH 128     // oversubscribed launch; teams claimed by XCD, rest exit
#define NT    256
#define NSLOT 4           // h slot rotation (WAR slack only)
#define HPITCH 34         // fp32 LDS h-transpose pitch (2-way banks = free)

typedef __attribute__((ext_vector_type(8))) short    short8;
typedef __attribute__((ext_vector_type(4))) float    float4v;
typedef __attribute__((ext_vector_type(4))) unsigned uint4v;

__device__ __forceinline__ unsigned short f2bf(float f) {
    union { float f; unsigned u; } v; v.f = f;
    unsigned r = v.u + 0x7FFFu + ((v.u >> 16) & 1u);   // RTNE
    return (unsigned short)(r >> 16);
}

__device__ __forceinline__ short8 cvt8(const float* p) {
    float4 u = *reinterpret_cast<const float4*>(p);
    float4 v = *reinterpret_cast<const float4*>(p + 4);
    short8 r;
    r[0] = (short)f2bf(u.x); r[1] = (short)f2bf(u.y);
    r[2] = (short)f2bf(u.z); r[3] = (short)f2bf(u.w);
    r[4] = (short)f2bf(v.x); r[5] = (short)f2bf(v.y);
    r[6] = (short)f2bf(v.z); r[7] = (short)f2bf(v.w);
    return r;
}

__device__ __forceinline__ unsigned long long pack4bf(float a, float b, float c, float d) {
    return (unsigned long long)f2bf(a)
         | ((unsigned long long)f2bf(b) << 16)
         | ((unsigned long long)f2bf(c) << 32)
         | ((unsigned long long)f2bf(d) << 48);
}

__device__ __forceinline__ float sigm(float v)  { return 1.0f / (1.0f + __expf(-v)); }
__device__ __forceinline__ float tanhf_(float v){ return 2.0f / (1.0f + __expf(-2.0f * v)) - 1.0f; }

// ---- sc0-only (bypass L1, coherent at the XCD-shared L2) memory helpers ----
__device__ __forceinline__ void st4_sc0(unsigned* p, unsigned v) {
    asm volatile("global_store_dword %0, %1, off sc0" :: "v"(p), "v"(v) : "memory");
}
__device__ __forceinline__ void st16_sc0(void* p, uint4v v) {
    asm volatile("global_store_dwordx4 %0, %1, off sc0" :: "v"(p), "v"(v) : "memory");
}
__device__ __forceinline__ unsigned ld32_sc0(const void* p) {
    unsigned r;
    asm volatile("global_load_dword %0, %1, off sc0\n\ts_waitcnt vmcnt(0)"
                 : "=v"(r) : "v"(p) : "memory");
    return r;
}
__device__ __forceinline__ void at_add_l2(unsigned* p, unsigned v) {
    // no sc1 -> RMW executes at the local (XCD) L2
    asm volatile("global_atomic_add %0, %1, off" :: "v"(p), "v"(v) : "memory");
}
// issue 8x dwordx4 sc0 loads (values valid only after an explicit s_waitcnt vmcnt(0))
// NOTE gfx950 syntax: offset: immediate must precede the cache flags (sc0)
__device__ __forceinline__ void ld_h_8x16_sc0(const char* src, uint4v out[8]) {
    const char* src2 = src + 4096;
    asm volatile(
        "global_load_dwordx4 %0, %[a], off sc0\n\t"
        "global_load_dwordx4 %1, %[a], off offset:1024 sc0\n\t"
        "global_load_dwordx4 %2, %[a], off offset:2048 sc0\n\t"
        "global_load_dwordx4 %3, %[a], off offset:3072 sc0\n\t"
        "global_load_dwordx4 %4, %[b], off sc0\n\t"
        "global_load_dwordx4 %5, %[b], off offset:1024 sc0\n\t"
        "global_load_dwordx4 %6, %[b], off offset:2048 sc0\n\t"
        "global_load_dwordx4 %7, %[b], off offset:3072 sc0"
        : "=&v"(out[0]), "=&v"(out[1]), "=&v"(out[2]), "=&v"(out[3]),
          "=&v"(out[4]), "=&v"(out[5]), "=&v"(out[6]), "=&v"(out[7])
        : [a]"v"(src), [b]"v"(src2)
        : "memory");
}

// ---------------- prepass: x[B][T][I] fp32 -> xfrag[T][chunk16][lane64][8] bf16 ----------------
__global__ __launch_bounds__(256) void build_xfrag(const float* __restrict__ x,
                                                   unsigned short* __restrict__ xf) {
    const int t = blockIdx.x, tid = threadIdx.x;
#pragma unroll
    for (int rep = 0; rep < 4; ++rep) {
        const int eidx  = rep * 256 + tid;
        const int chunk = eidx >> 6, lf = eidx & 63;
        const int kstep = chunk >> 1, nh = chunk & 1;
        const int kq = lf >> 4, nm = lf & 15;
        const int b  = nh * 16 + nm;
        const int i0 = kstep * 32 + kq * 8;
        short8 v = cvt8(x + ((size_t)b * T_ + t) * I_ + i0);
        *reinterpret_cast<short8*>(xf + ((size_t)t * 16 + chunk) * 512 + lf * 8) = v;
    }
}

// ---------------- main persistent kernel ----------------
// ws layout (after 8MB xfrag + 256KB hfrag):
//   bar   [2][T]  u32   (agent-scope flags, memset)          off 0
//   ctl   [64]    u32   (gticket, regcnt, initflag[2]; memset) off 4096
//   table [128]   u32   (registration: xcd per ticket; memset) off 4352
//   l2bar [2][T]  u32   (L2-scope flags; kernel-zeroed)        off 5120
__global__ __launch_bounds__(NT, 1) void bilstm_mfma(
    const float* __restrict__ Wih_f, const float* __restrict__ Whh_f, const float* __restrict__ bias_f,
    const float* __restrict__ Wih_b, const float* __restrict__ Whh_b, const float* __restrict__ bias_b,
    float* __restrict__ out, float* __restrict__ ws) {

    __shared__ __align__(16) char  sAX[16 * 1024];      // x B-frags
    __shared__ __align__(16) char  sAH[32 * 1024];      // h B-frags
    __shared__ __align__(16) float sHT[B_ * HPITCH];    // fp32 h transpose [b][hid_local]
    __shared__ int s_role[3];                           // l2mode, d, pb

    const int tid  = threadIdx.x;
    const int lane = tid & 63;
    const int w    = tid >> 6;

    const unsigned short* xfrag = (const unsigned short*)ws;                     // 8 MB
    unsigned long long* hfrag = (unsigned long long*)((char*)ws + (size_t)T_ * 16 * 1024);
    const char* hfrag_b = (const char*)hfrag;                                    // 256 KB
    unsigned* bar   = (unsigned*)((char*)hfrag + (size_t)2 * NSLOT * 32 * 1024); // [2][T]
    unsigned* ctl   = bar + 1024;        // [0]=gticket [1]=regcnt [2]=initflag d0 [3]=initflag d1
    unsigned* table = bar + 1024 + 64;   // [NB_LAUNCH]
    unsigned* l2bar = bar + 1280;        // [2][T], 256B-aligned, dir stride 2KB

    // ---- registration: all NB_LAUNCH blocks are co-resident (1/CU), so this terminates ----
    if (tid == 0) {
        unsigned myxcd;
        asm volatile("s_getreg_b32 %0, hwreg(HW_REG_XCC_ID)" : "=s"(myxcd));
        myxcd &= 7u;
        unsigned g = __hip_atomic_fetch_add(&ctl[0], 1u, __ATOMIC_RELAXED, __HIP_MEMORY_SCOPE_AGENT);
        __hip_atomic_store(&table[g], myxcd, __ATOMIC_RELAXED, __HIP_MEMORY_SCOPE_AGENT);
        __hip_atomic_fetch_add(&ctl[1], 1u, __ATOMIC_RELEASE, __HIP_MEMORY_SCOPE_AGENT);
        while (__hip_atomic_load(&ctl[1], __ATOMIC_ACQUIRE, __HIP_MEMORY_SCOPE_AGENT) < NB_LAUNCH)
            __builtin_amdgcn_s_sleep(8);

        unsigned cnt[8] = {0, 0, 0, 0, 0, 0, 0, 0};
        int rank = 0;
        for (int k = 0; k < NB_LAUNCH; ++k) {
            unsigned e = __hip_atomic_load(&table[k], __ATOMIC_RELAXED, __HIP_MEMORY_SCOPE_AGENT) & 7u;
            cnt[e]++;
            if (k < (int)g && e == myxcd) rank++;
        }
        int x0 = 0;
        for (int x = 1; x < 8; ++x) if (cnt[x] > cnt[x0]) x0 = x;
        int x1 = -1;
        for (int x = 0; x < 8; ++x) if (x != x0 && (x1 < 0 || cnt[x] > cnt[x1])) x1 = x;

        int l2 = 0, dd = -1, pbb = -1;
        const bool both_on_x0 = cnt[x0] >= 32;
        const bool split2     = (cnt[x0] >= 16) && (x1 >= 0 && cnt[x1] >= 16);
        if (both_on_x0) {
            l2 = 1;
            if ((int)myxcd == x0 && rank < 32) { dd = rank >> 4; pbb = rank & 15; }
        } else if (split2) {
            l2 = 1;
            if ((int)myxcd == x0 && rank < 16)      { dd = 0; pbb = rank; }
            else if ((int)myxcd == x1 && rank < 16) { dd = 1; pbb = rank; }
        } else {
            if (g < 32) { dd = (int)(g & 1); pbb = (int)(g >> 1); }  // exact legacy mapping
        }
        s_role[0] = l2; s_role[1] = dd; s_role[2] = pbb;
    }
    __syncthreads();
    const int l2mode = s_role[0];
    const int d      = s_role[1];
    const int pb     = s_role[2];
    if (d < 0) return;                                   // uniform per block

    // ---- L2 flag zeroing through the hosting L2 (kills cross-dispatch staleness) ----
    if (l2mode && pb == 0) {
        unsigned* zp = l2bar + d * T_;
        st4_sc0(zp + tid, 0u);
        st4_sc0(zp + tid + 256, 0u);
        asm volatile("s_waitcnt vmcnt(0)" ::: "memory");
        __syncthreads();
        if (tid == 0)
            __hip_atomic_store(&ctl[2 + d], 1u, __ATOMIC_RELEASE, __HIP_MEMORY_SCOPE_AGENT);
    }

    const float* Wih = d ? Wih_b : Wih_f;
    const float* Whh = d ? Whh_b : Whh_f;
    const float* bia = d ? bias_b : bias_f;

    // ---- one-time: weights -> resident A-fragments (bf16) ----
    const int mA  = lane & 15;
    const int kqA = lane >> 4;
    const int gA  = mA & 3;
    const int gr0 = gA * H_ + 32 * pb + 8 * w + (mA >> 2);
    const int gr1 = gr0 + 4;

    short8 wx0[8], wx1[8], wh0[16], wh1[16];
#pragma unroll
    for (int kst = 0; kst < 8; ++kst) {
        wx0[kst] = cvt8(Wih + (size_t)gr0 * I_ + kst * 32 + kqA * 8);
        wx1[kst] = cvt8(Wih + (size_t)gr1 * I_ + kst * 32 + kqA * 8);
    }
#pragma unroll
    for (int kst = 0; kst < 16; ++kst) {
        wh0[kst] = cvt8(Whh + (size_t)gr0 * H_ + kst * 32 + kqA * 8);
        wh1[kst] = cvt8(Whh + (size_t)gr1 * H_ + kst * 32 + kqA * 8);
    }

    const int hid0 = 32 * pb + 8 * w + kqA;
    float4v bq0, bq1;
#pragma unroll
    for (int g2 = 0; g2 < 4; ++g2) {
        bq0[g2] = bia[g2 * H_ + hid0];
        bq1[g2] = bia[g2 * H_ + hid0 + 4];
    }

    // publisher mapping (tid<128): unit = 8 consecutive hid at fixed batch
    const int pub_b  = tid & 31;
    const int pub_r8 = tid >> 5;
    const unsigned pub_chunkL = pb * 2 + (pub_b >> 4);
    const unsigned pub_lf     = pub_r8 * 16 + (pub_b & 15);

    // wait for l2bar zeroing before any flag traffic
    if (l2mode) {
        if (tid == 0) {
            while (__hip_atomic_load(&ctl[2 + d], __ATOMIC_ACQUIRE, __HIP_MEMORY_SCOPE_AGENT) == 0u)
                __builtin_amdgcn_s_sleep(2);
        }
    }

    float c00 = 0.f, c01 = 0.f, c10 = 0.f, c11 = 0.f;
    __syncthreads();

    for (int t = 0; t < T_; ++t) {
        const int tx    = d ? (T_ - 1 - t) : t;
        const int slot  = t & (NSLOT - 1);
        const int pslot = (t - 1) & (NSLOT - 1);

        // ---- 1. stage x frags (plain cached loads; immutable data) ----
        {
            const char* src = (const char*)xfrag + ((size_t)tx * 16 + w * 4) * 1024 + lane * 16;
            uint4 xbuf[4];
#pragma unroll
            for (int c = 0; c < 4; ++c) xbuf[c] = *reinterpret_cast<const uint4*>(src + c * 1024);
#pragma unroll
            for (int c = 0; c < 4; ++c)
                *reinterpret_cast<uint4*>(sAX + (w * 4 + c) * 1024 + lane * 16) = xbuf[c];
        }

        // ---- 2. wait for h(t-1) ----
        if (t > 0 && tid == 0) {
            const int idx = d * T_ + (t - 1);
            if (l2mode) {
                int sp = 0;
                for (;;) {
                    if (ld32_sc0(l2bar + idx) >= PB) break;
                    if ((++sp & 15) == 0 &&
                        __hip_atomic_load(&bar[idx], __ATOMIC_RELAXED,
                                          __HIP_MEMORY_SCOPE_AGENT) >= PB) break;  // anti-hang
                    __builtin_amdgcn_s_sleep(1);
                }
            } else {
                while (__hip_atomic_load(&bar[idx], __ATOMIC_RELAXED,
                                         __HIP_MEMORY_SCOPE_AGENT) < PB)
                    __builtin_amdgcn_s_sleep(1);
            }
        }
        __syncthreads();   // (A)

        // ---- 3a. issue h-frag loads ----
        unsigned long long hbuf[16];
        uint4v hb16[8];
        if (t > 0) {
            const char* src = hfrag_b + ((size_t)(d * NSLOT + pslot) * 32 + w * 8) * 1024 + lane * 16;
            if (l2mode) {
                ld_h_8x16_sc0(src, hb16);          // sc0: bypass L1, hit shared L2
            } else {
#pragma unroll
                for (int c = 0; c < 8; ++c) {
                    hbuf[2 * c + 0] = __hip_atomic_load((const unsigned long long*)(src + c * 1024),
                                                        __ATOMIC_RELAXED, __HIP_MEMORY_SCOPE_AGENT);
                    hbuf[2 * c + 1] = __hip_atomic_load((const unsigned long long*)(src + c * 1024 + 8),
                                                        __ATOMIC_RELAXED, __HIP_MEMORY_SCOPE_AGENT);
                }
            }
        }

        // ---- 4. MFMA: x part (overlaps h loads in flight) ----
        float4v a00 = bq0, a01 = bq0, a10 = bq1, a11 = bq1;
#pragma unroll
        for (int kst = 0; kst < 8; ++kst) {
            short8 f0 = *reinterpret_cast<const short8*>(sAX + (kst * 2 + 0) * 1024 + lane * 16);
            short8 f1 = *reinterpret_cast<const short8*>(sAX + (kst * 2 + 1) * 1024 + lane * 16);
            a00 = __builtin_amdgcn_mfma_f32_16x16x32_bf16(wx0[kst], f0, a00, 0, 0, 0);
            a01 = __builtin_amdgcn_mfma_f32_16x16x32_bf16(wx0[kst], f1, a01, 0, 0, 0);
            a10 = __builtin_amdgcn_mfma_f32_16x16x32_bf16(wx1[kst], f0, a10, 0, 0, 0);
            a11 = __builtin_amdgcn_mfma_f32_16x16x32_bf16(wx1[kst], f1, a11, 0, 0, 0);
        }

        // ---- 3b. h frags -> LDS ----
        if (t > 0) {
            if (l2mode) {
                asm volatile("s_waitcnt vmcnt(0)" ::: "memory");
                __builtin_amdgcn_sched_barrier(0);
#pragma unroll
                for (int c = 0; c < 8; ++c)
                    *reinterpret_cast<uint4v*>(sAH + (w * 8 + c) * 1024 + lane * 16) = hb16[c];
            } else {
#pragma unroll
                for (int c = 0; c < 8; ++c) {
                    char* dst = sAH + (w * 8 + c) * 1024 + lane * 16;
                    *reinterpret_cast<unsigned long long*>(dst)     = hbuf[2 * c + 0];
                    *reinterpret_cast<unsigned long long*>(dst + 8) = hbuf[2 * c + 1];
                }
            }
        }
        __syncthreads();   // (B)

        // ---- 5. MFMA: h part ----
        if (t > 0) {
#pragma unroll
            for (int kst = 0; kst < 16; ++kst) {
                short8 f0 = *reinterpret_cast<const short8*>(sAH + (kst * 2 + 0) * 1024 + lane * 16);
                short8 f1 = *reinterpret_cast<const short8*>(sAH + (kst * 2 + 1) * 1024 + lane * 16);
                a00 = __builtin_amdgcn_mfma_f32_16x16x32_bf16(wh0[kst], f0, a00, 0, 0, 0);
                a01 = __builtin_amdgcn_mfma_f32_16x16x32_bf16(wh0[kst], f1, a01, 0, 0, 0);
                a10 = __builtin_amdgcn_mfma_f32_16x16x32_bf16(wh1[kst], f0, a10, 0, 0, 0);
                a11 = __builtin_amdgcn_mfma_f32_16x16x32_bf16(wh1[kst], f1, a11, 0, 0, 0);
            }
        }

        // ---- 6. LSTM cell ----
        float h00, h01, h10, h11;
        {
            float iv, fv, gv, ov, c;
            iv = sigm(a00[0]); fv = sigm(a00[1]); gv = tanhf_(a00[2]); ov = sigm(a00[3]);
            c = fv * c00 + iv * gv; c00 = c; h00 = ov * tanhf_(c);
            iv = sigm(a01[0]); fv = sigm(a01[1]); gv = tanhf_(a01[2]); ov = sigm(a01[3]);
            c = fv * c01 + iv * gv; c01 = c; h01 = ov * tanhf_(c);
            iv = sigm(a10[0]); fv = sigm(a10[1]); gv = tanhf_(a10[2]); ov = sigm(a10[3]);
            c = fv * c10 + iv * gv; c10 = c; h10 = ov * tanhf_(c);
            iv = sigm(a11[0]); fv = sigm(a11[1]); gv = tanhf_(a11[2]); ov = sigm(a11[3]);
            c = fv * c11 + iv * gv; c11 = c; h11 = ov * tanhf_(c);
        }

        // ---- 7. transpose h through LDS (fp32) ----
        {
            const int hl = 8 * w + kqA;
            const int bn = mA;
            sHT[(bn)      * HPITCH + hl]     = h00;
            sHT[(bn + 16) * HPITCH + hl]     = h01;
            sHT[(bn)      * HPITCH + hl + 4] = h10;
            sHT[(bn + 16) * HPITCH + hl + 4] = h11;
        }
        __syncthreads();   // (B2)

        // ---- 8. publish: 128 lanes, each one 16 B frag unit ----
        float2 f01, f23, f45, f67;
        if (tid < 128) {
            const float* rp = sHT + pub_b * HPITCH + 8 * pub_r8;
            f01 = *reinterpret_cast<const float2*>(rp + 0);
            f23 = *reinterpret_cast<const float2*>(rp + 2);
            f45 = *reinterpret_cast<const float2*>(rp + 4);
            f67 = *reinterpret_cast<const float2*>(rp + 6);
            const unsigned long long lo = pack4bf(f01.x, f01.y, f23.x, f23.y);
            const unsigned long long hi = pack4bf(f45.x, f45.y, f67.x, f67.y);
            char* dst = (char*)hfrag + ((size_t)((d * NSLOT + slot) * 32 + pub_chunkL)) * 1024
                      + pub_lf * 16;
            if (l2mode) {
                uint4v pv;
                pv[0] = (unsigned)lo; pv[1] = (unsigned)(lo >> 32);
                pv[2] = (unsigned)hi; pv[3] = (unsigned)(hi >> 32);
                st16_sc0(dst, pv);                               // lands in shared L2
                asm volatile("s_waitcnt vmcnt(0)" ::: "memory"); // own store drained
            } else {
                __hip_atomic_store((unsigned long long*)dst,       lo, __ATOMIC_RELAXED, __HIP_MEMORY_SCOPE_AGENT);
                __hip_atomic_store((unsigned long long*)(dst + 8), hi, __ATOMIC_RELAXED, __HIP_MEMORY_SCOPE_AGENT);
            }
        }
        __syncthreads();   // (C) all publishes drained

        // ---- 9. arrive ----
        if (tid == 0) {
            if (l2mode) at_add_l2(l2bar + d * T_ + t, 1u);       // L2-local flag (fast path)
            __hip_atomic_fetch_add(&bar[d * T_ + t], 1u, __ATOMIC_RELAXED,
                                   __HIP_MEMORY_SCOPE_AGENT);    // L3 flag (fallback/anti-hang)
        }

        // ---- 10. out stores (fp32) — after arrive, off critical path ----
        if (tid < 128) {
            float* op = out + ((size_t)pub_b * T_ + tx) * (2 * H_) + (size_t)d * H_
                      + 32 * pb + 8 * pub_r8;
            *reinterpret_cast<float4*>(op + 0) = make_float4(f01.x, f01.y, f23.x, f23.y);
            *reinterpret_cast<float4*>(op + 4) = make_float4(f45.x, f45.y, f67.x, f67.y);
        }
    }
}

extern "C" void kernel_launch(void* const* d_in, const int* in_sizes, int n_in,
                              void* d_out, int out_size, void* d_ws, size_t ws_size,
                              hipStream_t stream) {
    const float* x     = (const float*)d_in[0];
    const float* Wih_f = (const float*)d_in[1];
    const float* Whh_f = (const float*)d_in[2];
    const float* b_f   = (const float*)d_in[3];
    const float* Wih_b = (const float*)d_in[4];
    const float* Whh_b = (const float*)d_in[5];
    const float* b_b   = (const float*)d_in[6];
    float* out = (float*)d_out;

    const size_t xf_bytes = (size_t)T_ * 16 * 1024;          // 8 MB
    const size_t hf_bytes = (size_t)2 * NSLOT * 32 * 1024;   // 256 KB
    const size_t ctl_bytes = 5120;                           // bar + ctl + table (l2bar kernel-zeroed)

    hipMemsetAsync((char*)d_ws + xf_bytes + hf_bytes, 0, ctl_bytes, stream);

    hipLaunchKernelGGL(build_xfrag, dim3(T_), dim3(256), 0, stream,
                       x, (unsigned short*)d_ws);

    hipLaunchKernelGGL(bilstm_mfma, dim3(NB_LAUNCH), dim3(NT), 0, stream,
                       Wih_f, Whh_f, b_f, Wih_b, Whh_b, b_b, out, (float*)d_ws);
}